// Round 1
// baseline (472.215 us; speedup 1.0000x reference)
//
#include <hip/hip_runtime.h>

// PlainVoxels (VolSDF-style) fused renderer.
// One 64-lane wave per ray; lane == sample index (S = 64).
// Outputs (flat, concatenated, N = #rays):
//   [0      , 3N)   rendered_rgb     (N,3)
//   [3N     , 4N)   rendered_depth   (N,1)
//   [4N     , 7N)   rendered_normals (N,3)
//   [7N     , 8N)   acc              (N,1)
//   [8N     , 200N) sdf_grads        (N*S,3)
//   [200N   , 201N) near_out         (N,1)
//   [201N   , 202N) far_out          (N,1)

constexpr int   GRID_R   = 256;
constexpr float CELL     = 0.015f;
constexpr float ORIGIN   = -1.92f;   // -0.5 * 256 * 0.015
constexpr int   S        = 64;
constexpr float MIN_BETA = 0.015f;

// ---------------------------------------------------------------------------
// L3 (Infinity Cache) warmer. The harness's 1.25 GiB poison fill between
// iterations flushes the 256 MB MALL, so every render launch gathers from
// cold HBM at random-access throughput (~0.9 TB/s for 64-128B lines).
// A sequential stream of the grid runs at ~6.3 TB/s and read-allocates into
// L3, converting the render's scattered gathers into L3 hits.
// Grid = 335.5 MB > 256 MB L3, so stream edge x-slices FIRST and central
// slices LAST: the centre (highest sample density, rays_o ~ N(0, 0.5))
// survives eviction.
// Launch: 2048 blocks x 256 threads; 8 blocks per x-slice, 256 slices.
// One x-slice = 256*256*5 floats = 81920 float4 = 1.31 MB.
// ---------------------------------------------------------------------------
__global__ __launch_bounds__(256)
void prefetch_grid(const float4* __restrict__ g)
{
    const int slice_rank = blockIdx.x >> 3;          // 0..255, 0 streamed first
    const int sub        = blockIdx.x & 7;           // chunk within slice
    // rank 0,1 -> ix 0,255 (edges); rank 254,255 -> ix 127,128 (centre, last)
    const int ix = (slice_rank & 1) ? (255 - (slice_rank >> 1)) : (slice_rank >> 1);

    const size_t sliceBase = (size_t)ix * 81920;     // float4 units
    const size_t chunk     = 81920 / 8;              // 10240 float4 per block
    size_t i         = sliceBase + (size_t)sub * chunk + threadIdx.x;
    const size_t end = sliceBase + (size_t)(sub + 1) * chunk;

    float sink = 0.f;
    for (; i < end; i += 256) {                      // 40 coalesced 1KB/wave reads
        const float4 v = g[i];
        sink += v.x + v.y + v.z + v.w;
    }
    asm volatile("" :: "v"(sink));                   // keep loads live, no store
}

__global__ __launch_bounds__(256)
void render_rays(const float* __restrict__ grid,
                 const float* __restrict__ beta_p,
                 const float* __restrict__ rays_o,
                 const float* __restrict__ rays_d,
                 const float* __restrict__ rdn,
                 const float* __restrict__ near_p,
                 const float* __restrict__ far_p,
                 float* __restrict__ out,
                 int N)
{
    const int lane = threadIdx.x & 63;
    const int ray  = blockIdx.x * (blockDim.x >> 6) + (threadIdx.x >> 6);
    if (ray >= N) return;

    const float nearv = near_p[0];
    const float farv  = far_p[0];
    const float dt    = (farv - nearv) / (float)S;
    const float t_n   = nearv + (float)lane * dt;
    const float t_mid = 0.5f * (t_n + (t_n + dt));

    const float ox = rays_o[3 * ray + 0];
    const float oy = rays_o[3 * ray + 1];
    const float oz = rays_o[3 * ray + 2];
    const float dxr = rays_d[3 * ray + 0];
    const float dyr = rays_d[3 * ray + 1];
    const float dzr = rays_d[3 * ray + 2];

    // Sample position and grid coords
    const float px = ox + t_mid * dxr;
    const float py = oy + t_mid * dyr;
    const float pz = oz + t_mid * dzr;
    const float ux = (px - ORIGIN) / CELL;
    const float uy = (py - ORIGIN) / CELL;
    const float uz = (pz - ORIGIN) / CELL;

    const bool inb = (ux >= 0.f) && (ux <= (float)(GRID_R - 1)) &&
                     (uy >= 0.f) && (uy <= (float)(GRID_R - 1)) &&
                     (uz >= 0.f) && (uz <= (float)(GRID_R - 1));

    int ix = (int)floorf(ux); ix = ix < 0 ? 0 : (ix > GRID_R - 2 ? GRID_R - 2 : ix);
    int iy = (int)floorf(uy); iy = iy < 0 ? 0 : (iy > GRID_R - 2 ? GRID_R - 2 : iy);
    int iz = (int)floorf(uz); iz = iz < 0 ? 0 : (iz > GRID_R - 2 ? GRID_R - 2 : iz);
    const float fx = ux - (float)ix;
    const float fy = uy - (float)iy;
    const float fz = uz - (float)iz;
    const float mfx = 1.f - fx, mfy = 1.f - fy, mfz = 1.f - fz;

    // Gather 8 corners x 4 channels (ch 0 = sdf, ch 1..3 = rgb; ch 4 unused)
    const float* gp = grid + (size_t)(((ix << 8) + iy) << 8 | iz) * 5;
    float v[2][2][2][4];
#pragma unroll
    for (int a = 0; a < 2; ++a)
#pragma unroll
        for (int b = 0; b < 2; ++b)
#pragma unroll
            for (int c = 0; c < 2; ++c) {
                const float* p = gp + (size_t)(((a << 8) + b) << 8 | c) * 5;
                v[a][b][c][0] = p[0];
                v[a][b][c][1] = p[1];
                v[a][b][c][2] = p[2];
                v[a][b][c][3] = p[3];
            }

    // Trilinear interp, all 4 channels; keep ch0 intermediates for the gradient
    float feat[4];
    float c00_0, c10_0, c01_0, c11_0, c0_0, c1_0;
#pragma unroll
    for (int ch = 0; ch < 4; ++ch) {
        const float c00 = v[0][0][0][ch] * mfx + v[1][0][0][ch] * fx;
        const float c10 = v[0][1][0][ch] * mfx + v[1][1][0][ch] * fx;
        const float c01 = v[0][0][1][ch] * mfx + v[1][0][1][ch] * fx;
        const float c11 = v[0][1][1][ch] * mfx + v[1][1][1][ch] * fx;
        const float c0 = c00 * mfy + c10 * fy;
        const float c1 = c01 * mfy + c11 * fy;
        feat[ch] = c0 * mfz + c1 * fz;
        if (ch == 0) { c00_0 = c00; c10_0 = c10; c01_0 = c01; c11_0 = c11; c0_0 = c0; c1_0 = c1; }
    }

    // Analytic gradient of ch0 wrt world coords (jax.grad of the trilinear):
    const float dgx_u = ((v[1][0][0][0] - v[0][0][0][0]) * mfy + (v[1][1][0][0] - v[0][1][0][0]) * fy) * mfz +
                        ((v[1][0][1][0] - v[0][0][1][0]) * mfy + (v[1][1][1][0] - v[0][1][1][0]) * fy) * fz;
    const float dgy_u = (c10_0 - c00_0) * mfz + (c11_0 - c01_0) * fz;
    const float dgz_u = c1_0 - c0_0;
    const float gx = dgx_u / CELL;
    const float gy = dgy_u / CELL;
    const float gz = dgz_u / CELL;

    // sdf_grads output (unmasked, exactly like the reference autodiff)
    {
        float* go = out + (size_t)8 * N + ((size_t)ray * S + lane) * 3;
        go[0] = gx; go[1] = gy; go[2] = gz;
    }

    // normals
    const float nrm = sqrtf(gx * gx + gy * gy + gz * gz);
    const float dn = fmaxf(nrm, 1e-12f);
    const float nx = gx / dn, ny = gy / dn, nz = gz / dn;

    // Laplace-CDF density
    const float sdf = feat[0];
    const float beta_eff = MIN_BETA + fabsf(beta_p[0]);
    const float sgn = (sdf > 0.f) ? 1.f : ((sdf < 0.f) ? -1.f : 0.f);
    float sigma = (1.f / beta_eff) * (0.5f + 0.5f * sgn * expm1f(-fabsf(sdf) / beta_eff));
    sigma = inb ? sigma : 0.f;
    const float tau = sigma * dt;

    // Exclusive prefix-sum of tau along the ray (64-lane scan)
    float incl = tau;
#pragma unroll
    for (int off = 1; off < 64; off <<= 1) {
        const float t = __shfl_up(incl, off, 64);
        if (lane >= off) incl += t;
    }
    const float T     = expf(-(incl - tau));
    const float alpha = -expm1f(-tau);
    const float w     = T * alpha;

    // Wave reductions: rgb(3), depth, normals(3), acc
    float red[8];
    red[0] = w * feat[1];
    red[1] = w * feat[2];
    red[2] = w * feat[3];
    red[3] = w * t_mid;
    red[4] = w * nx;
    red[5] = w * ny;
    red[6] = w * nz;
    red[7] = w;
#pragma unroll
    for (int off = 32; off > 0; off >>= 1) {
#pragma unroll
        for (int k = 0; k < 8; ++k)
            red[k] += __shfl_down(red[k], off, 64);
    }

    if (lane == 0) {
        const float inv_rdn = 1.f / rdn[ray];
        out[3 * ray + 0] = red[0];
        out[3 * ray + 1] = red[1];
        out[3 * ray + 2] = red[2];
        out[(size_t)3 * N + ray] = red[3] * inv_rdn;
        out[(size_t)4 * N + 3 * ray + 0] = red[4];
        out[(size_t)4 * N + 3 * ray + 1] = red[5];
        out[(size_t)4 * N + 3 * ray + 2] = red[6];
        out[(size_t)7 * N + ray] = red[7];
        out[(size_t)200 * N + ray] = nearv * inv_rdn;
        out[(size_t)201 * N + ray] = farv * inv_rdn;
    }
}

extern "C" void kernel_launch(void* const* d_in, const int* in_sizes, int n_in,
                              void* d_out, int out_size, void* d_ws, size_t ws_size,
                              hipStream_t stream) {
    const float* grid   = (const float*)d_in[0];
    const float* beta   = (const float*)d_in[1];
    const float* rays_o = (const float*)d_in[2];
    const float* rays_d = (const float*)d_in[3];
    const float* rdn    = (const float*)d_in[4];
    const float* nearp  = (const float*)d_in[5];
    const float* farp   = (const float*)d_in[6];
    float* out = (float*)d_out;

    const int N = in_sizes[2] / 3;           // rays_o is (N,3)

    // Warm the Infinity Cache with a sequential stream of the grid
    // (edge slices first, centre last) before the scattered-gather render.
    prefetch_grid<<<2048, 256, 0, stream>>>((const float4*)grid);

    const int raysPerBlock = 4;              // 256 threads = 4 waves
    const int blocks = (N + raysPerBlock - 1) / raysPerBlock;
    render_rays<<<blocks, 256, 0, stream>>>(grid, beta, rays_o, rays_d, rdn,
                                            nearp, farp, out, N);
}

// Round 2
// 398.899 us; speedup vs baseline: 1.1838x; 1.1838x over previous
//
#include <hip/hip_runtime.h>

// PlainVoxels (VolSDF-style) fused renderer — corner-per-wave restructure.
//
// Round-1 finding: L3-warming the grid gave ZERO render speedup -> the
// scattered gather is not HBM-residency/latency bound in the data sense;
// the ~195us render is consistent only with the per-wave 8-load->waitcnt
// structure failing to overlap its gathers (16 waves/CU, 50% occupancy).
//
// New structure: one block = one ray = 8 waves (512 threads).
// Wave w handles corner (a,b,c) = (w>>2, (w>>1)&1, w&1) for all 64 samples
// (lane == sample). Everything downstream of the corner fetch is LINEAR in
// the corner values, so each wave computes a weighted partial:
//   feat_part[ch] = v[ch] * wx*wy*wz
//   dgx_part = v[0] * (+-1)*wy*wz   (sign = a ? + : -)
//   dgy_part = v[0] * wx*(+-1)*wz
//   dgz_part = v[0] * wx*wy*(+-1)
// Partials are summed through LDS; wave 0 runs the unchanged tail
// (sigma, 64-lane scan, weighted reductions, stores).
//
// Guarantees: one gather per wave -> inter-wave overlap by construction;
// 512-thread blocks, 4 blocks/CU -> 32 waves/CU (full occupancy).
//
// Outputs (flat, concatenated, N = #rays):
//   [0,3N) rgb  [3N,4N) depth  [4N,7N) normals  [7N,8N) acc
//   [8N,200N) sdf_grads (N*S,3)  [200N,201N) near  [201N,202N) far

constexpr int   GRID_R   = 256;
constexpr float CELL     = 0.015f;
constexpr float ORIGIN   = -1.92f;   // -0.5 * 256 * 0.015
constexpr int   S        = 64;
constexpr float MIN_BETA = 0.015f;

__global__ __launch_bounds__(512)
void render_rays(const float* __restrict__ grid,
                 const float* __restrict__ beta_p,
                 const float* __restrict__ rays_o,
                 const float* __restrict__ rays_d,
                 const float* __restrict__ rdn,
                 const float* __restrict__ near_p,
                 const float* __restrict__ far_p,
                 float* __restrict__ out,
                 int N)
{
    const int lane = threadIdx.x & 63;          // sample index
    const int w    = threadIdx.x >> 6;          // corner id 0..7
    const int ray  = blockIdx.x;
    if (ray >= N) return;                       // uniform across block

    // partials[corner][sample][k], k = feat0..3, dgx, dgy, dgz; pad to 9
    // words so lane-stride 9 is coprime with 32 banks (conflict-free).
    __shared__ float part[8][64][9];

    const int a = w >> 2;
    const int b = (w >> 1) & 1;
    const int c = w & 1;

    const float nearv = near_p[0];
    const float farv  = far_p[0];
    const float dt    = (farv - nearv) / (float)S;
    const float t_n   = nearv + (float)lane * dt;
    const float t_mid = 0.5f * (t_n + (t_n + dt));

    const float ox = rays_o[3 * ray + 0];
    const float oy = rays_o[3 * ray + 1];
    const float oz = rays_o[3 * ray + 2];
    const float dxr = rays_d[3 * ray + 0];
    const float dyr = rays_d[3 * ray + 1];
    const float dzr = rays_d[3 * ray + 2];

    const float px = ox + t_mid * dxr;
    const float py = oy + t_mid * dyr;
    const float pz = oz + t_mid * dzr;
    const float ux = (px - ORIGIN) / CELL;
    const float uy = (py - ORIGIN) / CELL;
    const float uz = (pz - ORIGIN) / CELL;

    const bool inb = (ux >= 0.f) && (ux <= (float)(GRID_R - 1)) &&
                     (uy >= 0.f) && (uy <= (float)(GRID_R - 1)) &&
                     (uz >= 0.f) && (uz <= (float)(GRID_R - 1));

    int ix = (int)floorf(ux); ix = ix < 0 ? 0 : (ix > GRID_R - 2 ? GRID_R - 2 : ix);
    int iy = (int)floorf(uy); iy = iy < 0 ? 0 : (iy > GRID_R - 2 ? GRID_R - 2 : iy);
    int iz = (int)floorf(uz); iz = iz < 0 ? 0 : (iz > GRID_R - 2 ? GRID_R - 2 : iz);
    const float fx = ux - (float)ix;
    const float fy = uy - (float)iy;
    const float fz = uz - (float)iz;
    const float mfx = 1.f - fx, mfy = 1.f - fy, mfz = 1.f - fz;

    // This wave's corner weights (linear-decomposition of trilinear + grad)
    const float wx = a ? fx : mfx;
    const float wy = b ? fy : mfy;
    const float wz = c ? fz : mfz;
    const float sx = a ? 1.f : -1.f;
    const float sy = b ? 1.f : -1.f;
    const float sz = c ? 1.f : -1.f;

    // Single gather: this corner, this sample. (idx sum then *5 == original)
    const float* p = grid +
        ((size_t)(((ix << 8) + iy) << 8 | iz) +
         (size_t)(((a  << 8) + b ) << 8 | c)) * 5;
    const float v0 = p[0];
    const float v1 = p[1];
    const float v2 = p[2];
    const float v3 = p[3];

    const float www = wx * wy * wz;
    part[w][lane][0] = v0 * www;
    part[w][lane][1] = v1 * www;
    part[w][lane][2] = v2 * www;
    part[w][lane][3] = v3 * www;
    part[w][lane][4] = v0 * (sx * wy * wz);
    part[w][lane][5] = v0 * (wx * sy * wz);
    part[w][lane][6] = v0 * (wx * wy * sz);

    __syncthreads();
    if (w != 0) return;                          // no barriers past this point

    float acc[7] = {0.f, 0.f, 0.f, 0.f, 0.f, 0.f, 0.f};
#pragma unroll
    for (int q = 0; q < 8; ++q)
#pragma unroll
        for (int k = 0; k < 7; ++k)
            acc[k] += part[q][lane][k];

    const float gx = acc[4] / CELL;
    const float gy = acc[5] / CELL;
    const float gz = acc[6] / CELL;

    // sdf_grads output (unmasked, exactly like the reference autodiff)
    {
        float* go = out + (size_t)8 * N + ((size_t)ray * S + lane) * 3;
        go[0] = gx; go[1] = gy; go[2] = gz;
    }

    // normals
    const float nrm = sqrtf(gx * gx + gy * gy + gz * gz);
    const float dn = fmaxf(nrm, 1e-12f);
    const float nx = gx / dn, ny = gy / dn, nz = gz / dn;

    // Laplace-CDF density
    const float sdf = acc[0];
    const float beta_eff = MIN_BETA + fabsf(beta_p[0]);
    const float sgn = (sdf > 0.f) ? 1.f : ((sdf < 0.f) ? -1.f : 0.f);
    float sigma = (1.f / beta_eff) * (0.5f + 0.5f * sgn * expm1f(-fabsf(sdf) / beta_eff));
    sigma = inb ? sigma : 0.f;
    const float tau = sigma * dt;

    // Exclusive prefix-sum of tau along the ray (64-lane scan)
    float incl = tau;
#pragma unroll
    for (int off = 1; off < 64; off <<= 1) {
        const float t = __shfl_up(incl, off, 64);
        if (lane >= off) incl += t;
    }
    const float T     = expf(-(incl - tau));
    const float alpha = -expm1f(-tau);
    const float wgt   = T * alpha;

    // Wave reductions: rgb(3), depth, normals(3), acc
    float red[8];
    red[0] = wgt * acc[1];
    red[1] = wgt * acc[2];
    red[2] = wgt * acc[3];
    red[3] = wgt * t_mid;
    red[4] = wgt * nx;
    red[5] = wgt * ny;
    red[6] = wgt * nz;
    red[7] = wgt;
#pragma unroll
    for (int off = 32; off > 0; off >>= 1) {
#pragma unroll
        for (int k = 0; k < 8; ++k)
            red[k] += __shfl_down(red[k], off, 64);
    }

    if (lane == 0) {
        const float inv_rdn = 1.f / rdn[ray];
        out[3 * ray + 0] = red[0];
        out[3 * ray + 1] = red[1];
        out[3 * ray + 2] = red[2];
        out[(size_t)3 * N + ray] = red[3] * inv_rdn;
        out[(size_t)4 * N + 3 * ray + 0] = red[4];
        out[(size_t)4 * N + 3 * ray + 1] = red[5];
        out[(size_t)4 * N + 3 * ray + 2] = red[6];
        out[(size_t)7 * N + ray] = red[7];
        out[(size_t)200 * N + ray] = nearv * inv_rdn;
        out[(size_t)201 * N + ray] = farv * inv_rdn;
    }
}

extern "C" void kernel_launch(void* const* d_in, const int* in_sizes, int n_in,
                              void* d_out, int out_size, void* d_ws, size_t ws_size,
                              hipStream_t stream) {
    const float* grid   = (const float*)d_in[0];
    const float* beta   = (const float*)d_in[1];
    const float* rays_o = (const float*)d_in[2];
    const float* rays_d = (const float*)d_in[3];
    const float* rdn    = (const float*)d_in[4];
    const float* nearp  = (const float*)d_in[5];
    const float* farp   = (const float*)d_in[6];
    float* out = (float*)d_out;

    const int N = in_sizes[2] / 3;           // rays_o is (N,3)

    // One block per ray: 8 waves, one corner each.
    render_rays<<<N, 512, 0, stream>>>(grid, beta, rays_o, rays_d, rdn,
                                       nearp, farp, out, N);
}